// Round 2
// baseline (3429.406 us; speedup 1.0000x reference)
//
#include <hip/hip_runtime.h>
#include <hip/hip_bf16.h>

// Problem constants
#define TT   256
#define BB   1024
#define OBS  64
#define HH   128
#define AA   32
#define NN   (TT*BB)          // 262144

__device__ __forceinline__ float sigmoidf_(float x) {
    return 1.0f / (1.0f + __expf(-x));
}
__device__ __forceinline__ float tanhf_(float x) {
    float ax = fabsf(x);
    float e  = __expf(-2.0f * ax);
    float t  = (1.0f - e) / (1.0f + e);
    return copysignf(t, x);
}

// ---------------------------------------------------------------------------
// Kernel 1: trunk + xg precompute.
//   hidden = relu(relu(x@W1+b1)@W2+b2)            [N,128]
//   xg     = hidden @ w_ih.T + (b_ih + b_hh)      [N,512]  -> bf16 in ws
// ---------------------------------------------------------------------------
__global__ __launch_bounds__(256) void trunk_kernel(
    const float* __restrict__ x,
    const float* __restrict__ W1, const float* __restrict__ b1,
    const float* __restrict__ W2, const float* __restrict__ b2,
    const float* __restrict__ w_ih,
    const float* __restrict__ b_ih, const float* __restrict__ b_hh,
    __hip_bfloat16* __restrict__ xg)
{
    __shared__ float xs[64][64];     // 16KB
    __shared__ float h1s[64][128];   // 32KB
    __shared__ float h2s[64][128];   // 32KB

    const int tid = threadIdx.x;
    const int tx = tid & 15;         // output-col group
    const int ty = tid >> 4;         // row group (4 rows each)
    const size_t r0 = (size_t)blockIdx.x * 64;

    // stage x tile [64][64]
    {
        const float4* xsrc = (const float4*)(x + r0 * OBS);
        float4* xdst = (float4*)&xs[0][0];
        #pragma unroll
        for (int i = 0; i < 4; ++i) xdst[i*256 + tid] = xsrc[i*256 + tid];
    }
    __syncthreads();

    // phase 1: h1 = relu(x @ W1 + b1), K=64
    {
        float acc[4][8];
        #pragma unroll
        for (int i = 0; i < 4; ++i)
            #pragma unroll
            for (int j = 0; j < 8; ++j) acc[i][j] = 0.0f;
        #pragma unroll 4
        for (int k = 0; k < 64; ++k) {
            float4 wa = *(const float4*)(W1 + k*128 + tx*8);
            float4 wb = *(const float4*)(W1 + k*128 + tx*8 + 4);
            #pragma unroll
            for (int i = 0; i < 4; ++i) {
                float xv = xs[ty*4 + i][k];
                acc[i][0] = fmaf(xv, wa.x, acc[i][0]);
                acc[i][1] = fmaf(xv, wa.y, acc[i][1]);
                acc[i][2] = fmaf(xv, wa.z, acc[i][2]);
                acc[i][3] = fmaf(xv, wa.w, acc[i][3]);
                acc[i][4] = fmaf(xv, wb.x, acc[i][4]);
                acc[i][5] = fmaf(xv, wb.y, acc[i][5]);
                acc[i][6] = fmaf(xv, wb.z, acc[i][6]);
                acc[i][7] = fmaf(xv, wb.w, acc[i][7]);
            }
        }
        #pragma unroll
        for (int j = 0; j < 8; ++j) {
            float bj = b1[tx*8 + j];
            #pragma unroll
            for (int i = 0; i < 4; ++i)
                h1s[ty*4 + i][tx*8 + j] = fmaxf(acc[i][j] + bj, 0.0f);
        }
    }
    __syncthreads();

    // phase 2: h2 = relu(h1 @ W2 + b2), K=128
    {
        float acc[4][8];
        #pragma unroll
        for (int i = 0; i < 4; ++i)
            #pragma unroll
            for (int j = 0; j < 8; ++j) acc[i][j] = 0.0f;
        #pragma unroll 4
        for (int k = 0; k < 128; ++k) {
            float4 wa = *(const float4*)(W2 + k*128 + tx*8);
            float4 wb = *(const float4*)(W2 + k*128 + tx*8 + 4);
            #pragma unroll
            for (int i = 0; i < 4; ++i) {
                float xv = h1s[ty*4 + i][k];
                acc[i][0] = fmaf(xv, wa.x, acc[i][0]);
                acc[i][1] = fmaf(xv, wa.y, acc[i][1]);
                acc[i][2] = fmaf(xv, wa.z, acc[i][2]);
                acc[i][3] = fmaf(xv, wa.w, acc[i][3]);
                acc[i][4] = fmaf(xv, wb.x, acc[i][4]);
                acc[i][5] = fmaf(xv, wb.y, acc[i][5]);
                acc[i][6] = fmaf(xv, wb.z, acc[i][6]);
                acc[i][7] = fmaf(xv, wb.w, acc[i][7]);
            }
        }
        #pragma unroll
        for (int j = 0; j < 8; ++j) {
            float bj = b2[tx*8 + j];
            #pragma unroll
            for (int i = 0; i < 4; ++i)
                h2s[ty*4 + i][tx*8 + j] = fmaxf(acc[i][j] + bj, 0.0f);
        }
    }
    __syncthreads();

    // phase 3: xg = h2 @ w_ih.T + (b_ih+b_hh); 4 column passes of 128
    for (int jb = 0; jb < 4; ++jb) {
        const int j0 = jb * 128;
        float acc[4][8];
        #pragma unroll
        for (int jj = 0; jj < 8; ++jj) {
            int j = j0 + tx*8 + jj;
            float bias = b_ih[j] + b_hh[j];
            #pragma unroll
            for (int i = 0; i < 4; ++i) acc[i][jj] = bias;
        }
        #pragma unroll 2
        for (int k4 = 0; k4 < 32; ++k4) {
            float4 h4[4];
            #pragma unroll
            for (int i = 0; i < 4; ++i)
                h4[i] = *(const float4*)&h2s[ty*4 + i][k4*4];
            #pragma unroll
            for (int jj = 0; jj < 8; ++jj) {
                float4 wv = *(const float4*)(w_ih + (size_t)(j0 + tx*8 + jj)*128 + k4*4);
                #pragma unroll
                for (int i = 0; i < 4; ++i) {
                    acc[i][jj] = fmaf(h4[i].x, wv.x, acc[i][jj]);
                    acc[i][jj] = fmaf(h4[i].y, wv.y, acc[i][jj]);
                    acc[i][jj] = fmaf(h4[i].z, wv.z, acc[i][jj]);
                    acc[i][jj] = fmaf(h4[i].w, wv.w, acc[i][jj]);
                }
            }
        }
        #pragma unroll
        for (int i = 0; i < 4; ++i) {
            union { int4 v; unsigned short s[8]; } u;
            #pragma unroll
            for (int jj = 0; jj < 8; ++jj) {
                __hip_bfloat16 hb = __float2bfloat16(acc[i][jj]);
                u.s[jj] = *reinterpret_cast<unsigned short*>(&hb);
            }
            *(int4*)(xg + (r0 + ty*4 + i)*512 + j0 + tx*8) = u.v;
        }
    }
}

// ---------------------------------------------------------------------------
// Kernel 2: LSTM scan + fused heads.
// 256 blocks x 512 threads; block owns 4 batch rows for all 256 steps.
// Thread tid holds w_hh row tid (128 floats) in registers; h/c in LDS.
// Heads (logits/softmax/entropy/value) computed on threads 0..127 each step.
// ---------------------------------------------------------------------------
__global__ __launch_bounds__(512, 2) void lstm_kernel(
    const __hip_bfloat16* __restrict__ xg,  // [N,512] bf16
    const float* __restrict__ w_hh,         // [512,128]
    const int* __restrict__ done,           // [N]
    const int* __restrict__ action,         // [N]
    const int* __restrict__ mask,           // [N,32] bool passed as int32
    const float* __restrict__ h0,           // [B,128]
    const float* __restrict__ c0,           // [B,128]
    const float* __restrict__ Wa,           // [128,32]
    const float* __restrict__ ba,           // [32]
    const float* __restrict__ Wc,           // [128]
    const float* __restrict__ bc,           // [1]
    float* __restrict__ out)                // lp N | ent N | val N | hN B*H | cN B*H
{
    __shared__ float hls[4][128];
    __shared__ float cls[4][128];
    __shared__ float gls[4][512];
    __shared__ float WaS[128*32];
    __shared__ float baS[32];
    __shared__ float WcS[128];
    __shared__ float bcS;

    const int tid = threadIdx.x;
    const int b0 = blockIdx.x * 4;

    // w_hh row -> registers (fully static indexing; stays in VGPRs)
    float wv[128];
    {
        const float4* wr = (const float4*)(w_hh + (size_t)tid * 128);
        #pragma unroll
        for (int q = 0; q < 32; ++q) {
            float4 v = wr[q];
            wv[4*q+0] = v.x; wv[4*q+1] = v.y; wv[4*q+2] = v.z; wv[4*q+3] = v.w;
        }
    }
    for (int i = tid; i < 128*32; i += 512) WaS[i] = Wa[i];
    if (tid < 32)  baS[tid] = ba[tid];
    if (tid < 128) WcS[tid] = Wc[tid];
    if (tid == 0)  bcS = bc[0];

    const int r = tid >> 7;       // 0..3  (batch row within block)
    const int u = tid & 127;      // 0..127 (hidden unit)
    hls[r][u] = h0[(size_t)(b0 + r)*128 + u];
    cls[r][u] = c0[(size_t)(b0 + r)*128 + u];
    __syncthreads();

    for (int t = 0; t < TT; ++t) {
        const size_t base = (size_t)t * BB + b0;

        // done-based state reset (applies BEFORE gates)
        float keep = (done[base + r] != 0) ? 0.0f : 1.0f;
        hls[r][u] *= keep;
        cls[r][u] *= keep;
        __syncthreads();

        // g[rr][tid] = xg[rr][tid] + sum_k h[rr][k] * w_hh[tid][k]
        float acc0 = __bfloat162float(xg[(base + 0)*512 + tid]);
        float acc1 = __bfloat162float(xg[(base + 1)*512 + tid]);
        float acc2 = __bfloat162float(xg[(base + 2)*512 + tid]);
        float acc3 = __bfloat162float(xg[(base + 3)*512 + tid]);
        #pragma unroll
        for (int k4 = 0; k4 < 32; ++k4) {
            float4 hv0 = *(const float4*)&hls[0][4*k4];
            float4 hv1 = *(const float4*)&hls[1][4*k4];
            float4 hv2 = *(const float4*)&hls[2][4*k4];
            float4 hv3 = *(const float4*)&hls[3][4*k4];
            acc0 = fmaf(wv[4*k4+0], hv0.x, acc0);
            acc1 = fmaf(wv[4*k4+0], hv1.x, acc1);
            acc2 = fmaf(wv[4*k4+0], hv2.x, acc2);
            acc3 = fmaf(wv[4*k4+0], hv3.x, acc3);
            acc0 = fmaf(wv[4*k4+1], hv0.y, acc0);
            acc1 = fmaf(wv[4*k4+1], hv1.y, acc1);
            acc2 = fmaf(wv[4*k4+1], hv2.y, acc2);
            acc3 = fmaf(wv[4*k4+1], hv3.y, acc3);
            acc0 = fmaf(wv[4*k4+2], hv0.z, acc0);
            acc1 = fmaf(wv[4*k4+2], hv1.z, acc1);
            acc2 = fmaf(wv[4*k4+2], hv2.z, acc2);
            acc3 = fmaf(wv[4*k4+2], hv3.z, acc3);
            acc0 = fmaf(wv[4*k4+3], hv0.w, acc0);
            acc1 = fmaf(wv[4*k4+3], hv1.w, acc1);
            acc2 = fmaf(wv[4*k4+3], hv2.w, acc2);
            acc3 = fmaf(wv[4*k4+3], hv3.w, acc3);
        }
        gls[0][tid] = acc0;
        gls[1][tid] = acc1;
        gls[2][tid] = acc2;
        gls[3][tid] = acc3;
        __syncthreads();

        // gate update: thread handles (r,u); torch gate order i,f,g,o
        {
            float gi = gls[r][u];
            float gf = gls[r][128 + u];
            float gg = gls[r][256 + u];
            float go = gls[r][384 + u];
            float cn = sigmoidf_(gf) * cls[r][u] + sigmoidf_(gi) * tanhf_(gg);
            float hn = sigmoidf_(go) * tanhf_(cn);
            cls[r][u] = cn;
            hls[r][u] = hn;
        }
        __syncthreads();

        // heads: threads 0..127 -> (row rr, logit j)
        if (tid < 128) {
            int rr = tid >> 5, j = tid & 31;
            float lg = baS[j];
            #pragma unroll 8
            for (int k = 0; k < 128; ++k)
                lg = fmaf(hls[rr][k], WaS[k*32 + j], lg);
            int m = mask[(base + rr)*32 + j];
            if (m == 0) lg = -1e8f;
            float mx = lg;
            #pragma unroll
            for (int off = 16; off > 0; off >>= 1)
                mx = fmaxf(mx, __shfl_xor(mx, off, 32));
            float e = __expf(lg - mx);
            float s = e;
            #pragma unroll
            for (int off = 16; off > 0; off >>= 1)
                s += __shfl_xor(s, off, 32);
            float lse = __logf(s);
            float logp = lg - mx - lse;
            float p = e / s;
            float entp = -p * logp;
            #pragma unroll
            for (int off = 16; off > 0; off >>= 1)
                entp += __shfl_xor(entp, off, 32);
            int act = action[base + rr];
            if (j == act) out[base + rr] = logp;                 // lp
            if (j == 0)   out[(size_t)NN + base + rr] = entp;    // entropy
            // value: 32 lanes x 4 k each
            float vp = 0.0f;
            #pragma unroll
            for (int q = 0; q < 4; ++q)
                vp = fmaf(hls[rr][j*4 + q], WcS[j*4 + q], vp);
            #pragma unroll
            for (int off = 16; off > 0; off >>= 1)
                vp += __shfl_xor(vp, off, 32);
            if (j == 0) out[2*(size_t)NN + base + rr] = vp + bcS;
        }
        __syncthreads();
    }

    // final states hN, cN
    out[3*(size_t)NN + (size_t)(b0 + r)*128 + u] = hls[r][u];
    out[3*(size_t)NN + (size_t)BB*HH + (size_t)(b0 + r)*128 + u] = cls[r][u];
}

extern "C" void kernel_launch(void* const* d_in, const int* in_sizes, int n_in,
                              void* d_out, int out_size, void* d_ws, size_t ws_size,
                              hipStream_t stream) {
    const float* x      = (const float*)d_in[0];
    const int*   done   = (const int*)d_in[1];
    const int*   action = (const int*)d_in[2];
    const int*   mask   = (const int*)d_in[3];
    const float* h0     = (const float*)d_in[4];
    const float* c0     = (const float*)d_in[5];
    const float* W1     = (const float*)d_in[6];
    const float* b1     = (const float*)d_in[7];
    const float* W2     = (const float*)d_in[8];
    const float* b2     = (const float*)d_in[9];
    const float* w_ih   = (const float*)d_in[10];
    const float* w_hh   = (const float*)d_in[11];
    const float* b_ih   = (const float*)d_in[12];
    const float* b_hh   = (const float*)d_in[13];
    const float* Wa     = (const float*)d_in[14];
    const float* ba     = (const float*)d_in[15];
    const float* Wc     = (const float*)d_in[16];
    const float* bc     = (const float*)d_in[17];

    __hip_bfloat16* xg = (__hip_bfloat16*)d_ws;  // [N,512] bf16 = 268MB

    trunk_kernel<<<NN/64, 256, 0, stream>>>(x, W1, b1, W2, b2, w_ih, b_ih, b_hh, xg);
    lstm_kernel<<<BB/4, 512, 0, stream>>>(xg, w_hh, done, action, mask, h0, c0,
                                          Wa, ba, Wc, bc, (float*)d_out);
}

// Round 3
// 1475.240 us; speedup vs baseline: 2.3246x; 2.3246x over previous
//
#include <hip/hip_runtime.h>
#include <hip/hip_bf16.h>

// Problem constants
#define TT   256
#define BB   1024
#define OBS  64
#define HH   128
#define AA   32
#define NN   (TT*BB)          // 262144

typedef __bf16 bf16x8 __attribute__((ext_vector_type(8)));
typedef float  f32x4  __attribute__((ext_vector_type(4)));

__device__ __forceinline__ float sigmoidf_(float x) {
    return 1.0f / (1.0f + __expf(-x));
}
__device__ __forceinline__ float tanhf_(float x) {
    float ax = fabsf(x);
    float e  = __expf(-2.0f * ax);
    float t  = (1.0f - e) / (1.0f + e);
    return copysignf(t, x);
}
__device__ __forceinline__ __hip_bfloat16 f2b(float v) { return __float2bfloat16(v); }
__device__ __forceinline__ bf16x8 ldb(const __hip_bfloat16* p) {
    return *reinterpret_cast<const bf16x8*>(p);
}
__device__ __forceinline__ f32x4 mm16(bf16x8 a, bf16x8 b, f32x4 c) {
    return __builtin_amdgcn_mfma_f32_16x16x32_bf16(a, b, c, 0, 0, 0);
}

// ---------------------------------------------------------------------------
// Kernel 1 (MFMA bf16): hidden = relu(relu(x@W1+b1)@W2+b2);
//                       xg = hidden @ w_ih.T + (b_ih+b_hh)  -> bf16 [N,512]
// 512 threads (8 waves), 128 rows/block, grid 2048.
// LDS (109.5KB, 1 block/CU), padded pitches (+8 bf16) to break bank conflicts:
//   [0     ,18432)  xb  [128][72]   (A for L1)      } later W2T [128][136]
//   [18432 ,36864)  W1T [128][72]   (B for L1)      }  and wihb chunk
//   [36864 ,71680)  h1b [128][136]  (A for L2)      }  [256][136] spans 0..69632
//   [71680 ,106496) h2b [128][136]  (A for L3)
//   [106496,109568) biases fp32: b1[128], b2[128], (b_ih+b_hh)[512]
// MFMA 16x16x32 bf16: A lane: row=l&15, k=(l>>4)*8+i ; B lane: col=l&15, same k
// C/D lane: col=l&15, row=(l>>4)*4+reg  (m89-verified)
// ---------------------------------------------------------------------------
__global__ __launch_bounds__(512) void trunk_kernel(
    const float* __restrict__ x,
    const float* __restrict__ W1, const float* __restrict__ b1,
    const float* __restrict__ W2, const float* __restrict__ b2,
    const float* __restrict__ w_ih,
    const float* __restrict__ b_ih, const float* __restrict__ b_hh,
    __hip_bfloat16* __restrict__ xg)
{
    __shared__ __align__(16) char smem[109568];
    __hip_bfloat16 (*xb)[72]    = (__hip_bfloat16(*)[72])(smem);
    __hip_bfloat16 (*W1T)[72]   = (__hip_bfloat16(*)[72])(smem + 18432);
    __hip_bfloat16 (*W2T)[136]  = (__hip_bfloat16(*)[136])(smem);
    __hip_bfloat16 (*h1b)[136]  = (__hip_bfloat16(*)[136])(smem + 36864);
    __hip_bfloat16 (*h2b)[136]  = (__hip_bfloat16(*)[136])(smem + 71680);
    __hip_bfloat16 (*wihb)[136] = (__hip_bfloat16(*)[136])(smem);
    float* sb1  = (float*)(smem + 106496);
    float* sb2  = sb1 + 128;
    float* sbih = sb2 + 128;

    const int tid  = threadIdx.x;
    const int lane = tid & 63;
    const int w    = tid >> 6;          // wave 0..7
    const int m0   = w * 16;            // wave's row tile
    const int lm   = lane & 15;
    const int lk   = (lane >> 4) * 8;
    const size_t r0 = (size_t)blockIdx.x * 128;

    // ---- stage x [128][64] fp32 -> bf16 LDS ----
    {
        int row = tid >> 2, seg = tid & 3;
        const float4* xs = (const float4*)(x + (r0 + row) * OBS + seg * 16);
        float4 v0 = xs[0], v1 = xs[1], v2 = xs[2], v3 = xs[3];
        union { bf16x8 v[2]; __hip_bfloat16 h[16]; } u;
        u.h[0]=f2b(v0.x); u.h[1]=f2b(v0.y); u.h[2]=f2b(v0.z); u.h[3]=f2b(v0.w);
        u.h[4]=f2b(v1.x); u.h[5]=f2b(v1.y); u.h[6]=f2b(v1.z); u.h[7]=f2b(v1.w);
        u.h[8]=f2b(v2.x); u.h[9]=f2b(v2.y); u.h[10]=f2b(v2.z); u.h[11]=f2b(v2.w);
        u.h[12]=f2b(v3.x); u.h[13]=f2b(v3.y); u.h[14]=f2b(v3.z); u.h[15]=f2b(v3.w);
        *(bf16x8*)&xb[row][seg*16]     = u.v[0];
        *(bf16x8*)&xb[row][seg*16 + 8] = u.v[1];
    }
    // ---- stage W1T[n][k] bf16 (transpose of W1 [64][128]) ----
    #pragma unroll
    for (int kk = 0; kk < 4; ++kk) {
        int k = (tid >> 5) + kk * 16;
        int n0 = (tid & 31) * 4;
        float4 wv4 = *(const float4*)(W1 + k * HH + n0);
        W1T[n0+0][k] = f2b(wv4.x); W1T[n0+1][k] = f2b(wv4.y);
        W1T[n0+2][k] = f2b(wv4.z); W1T[n0+3][k] = f2b(wv4.w);
    }
    // ---- biases ----
    if (tid < 128) { sb1[tid] = b1[tid]; sb2[tid] = b2[tid]; }
    sbih[tid] = b_ih[tid] + b_hh[tid];
    __syncthreads();

    // ---- L1: h1 = relu(x @ W1 + b1), K=64 ----
    {
        bf16x8 a0 = ldb(&xb[m0 + lm][lk]);
        bf16x8 a1 = ldb(&xb[m0 + lm][32 + lk]);
        #pragma unroll
        for (int ct = 0; ct < 8; ++ct) {
            bf16x8 bv0 = ldb(&W1T[ct*16 + lm][lk]);
            bf16x8 bv1 = ldb(&W1T[ct*16 + lm][32 + lk]);
            f32x4 acc = {0.f, 0.f, 0.f, 0.f};
            acc = mm16(a0, bv0, acc);
            acc = mm16(a1, bv1, acc);
            float bias = sb1[ct*16 + lm];
            int rb = m0 + (lane >> 4) * 4;
            #pragma unroll
            for (int rr = 0; rr < 4; ++rr)
                h1b[rb + rr][ct*16 + lm] = f2b(fmaxf(acc[rr] + bias, 0.f));
        }
    }
    __syncthreads();

    // ---- stage W2T[n][k] bf16 (overwrites xb/W1T) ----
    #pragma unroll
    for (int kk = 0; kk < 8; ++kk) {
        int k = (tid >> 5) + kk * 16;
        int n0 = (tid & 31) * 4;
        float4 wv4 = *(const float4*)(W2 + k * HH + n0);
        W2T[n0+0][k] = f2b(wv4.x); W2T[n0+1][k] = f2b(wv4.y);
        W2T[n0+2][k] = f2b(wv4.z); W2T[n0+3][k] = f2b(wv4.w);
    }
    __syncthreads();

    // ---- L2: h2 = relu(h1 @ W2 + b2), K=128 ----
    {
        bf16x8 a[4];
        #pragma unroll
        for (int kt = 0; kt < 4; ++kt) a[kt] = ldb(&h1b[m0 + lm][kt*32 + lk]);
        #pragma unroll
        for (int ct = 0; ct < 8; ++ct) {
            f32x4 acc = {0.f, 0.f, 0.f, 0.f};
            #pragma unroll
            for (int kt = 0; kt < 4; ++kt)
                acc = mm16(a[kt], ldb(&W2T[ct*16 + lm][kt*32 + lk]), acc);
            float bias = sb2[ct*16 + lm];
            int rb = m0 + (lane >> 4) * 4;
            #pragma unroll
            for (int rr = 0; rr < 4; ++rr)
                h2b[rb + rr][ct*16 + lm] = f2b(fmaxf(acc[rr] + bias, 0.f));
        }
    }
    __syncthreads();

    // ---- L3: xg = h2 @ w_ih.T + bias, two 256-col chunks ----
    bf16x8 a3[4];
    #pragma unroll
    for (int kt = 0; kt < 4; ++kt) a3[kt] = ldb(&h2b[m0 + lm][kt*32 + lk]);

    for (int jc = 0; jc < 2; ++jc) {
        // stage w_ih rows [jc*256, jc*256+256) as bf16 [256][136] (B-layout: row=j, k contiguous)
        #pragma unroll
        for (int jj = 0; jj < 4; ++jj) {
            int j = jj * 64 + (tid >> 3);
            int seg = tid & 7;
            const float4* ws = (const float4*)(w_ih + (size_t)(jc*256 + j) * HH + seg * 16);
            float4 v0 = ws[0], v1 = ws[1], v2 = ws[2], v3 = ws[3];
            union { bf16x8 v[2]; __hip_bfloat16 h[16]; } u;
            u.h[0]=f2b(v0.x); u.h[1]=f2b(v0.y); u.h[2]=f2b(v0.z); u.h[3]=f2b(v0.w);
            u.h[4]=f2b(v1.x); u.h[5]=f2b(v1.y); u.h[6]=f2b(v1.z); u.h[7]=f2b(v1.w);
            u.h[8]=f2b(v2.x); u.h[9]=f2b(v2.y); u.h[10]=f2b(v2.z); u.h[11]=f2b(v2.w);
            u.h[12]=f2b(v3.x); u.h[13]=f2b(v3.y); u.h[14]=f2b(v3.z); u.h[15]=f2b(v3.w);
            *(bf16x8*)&wihb[j][seg*16]     = u.v[0];
            *(bf16x8*)&wihb[j][seg*16 + 8] = u.v[1];
        }
        __syncthreads();

        #pragma unroll
        for (int ct = 0; ct < 16; ++ct) {
            f32x4 acc = {0.f, 0.f, 0.f, 0.f};
            #pragma unroll
            for (int kt = 0; kt < 4; ++kt)
                acc = mm16(a3[kt], ldb(&wihb[ct*16 + lm][kt*32 + lk]), acc);
            int j = jc*256 + ct*16 + lm;
            float bias = sbih[j];
            size_t rb = r0 + m0 + (lane >> 4) * 4;
            #pragma unroll
            for (int rr = 0; rr < 4; ++rr)
                xg[(rb + rr) * 512 + j] = f2b(acc[rr] + bias);
        }
        __syncthreads();
    }
}

// ---------------------------------------------------------------------------
// Kernel 2: LSTM scan + fused heads, with t+1 prefetch of xg/done/mask/action.
// 256 blocks x 512 threads; block owns 4 batch rows for all 256 steps.
// ---------------------------------------------------------------------------
__global__ __launch_bounds__(512, 2) void lstm_kernel(
    const __hip_bfloat16* __restrict__ xg,  // [N,512] bf16
    const float* __restrict__ w_hh,         // [512,128]
    const int* __restrict__ done,           // [N]
    const int* __restrict__ action,         // [N]
    const int* __restrict__ mask,           // [N,32] bool passed as int32
    const float* __restrict__ h0,
    const float* __restrict__ c0,
    const float* __restrict__ Wa,           // [128,32]
    const float* __restrict__ ba,
    const float* __restrict__ Wc,           // [128]
    const float* __restrict__ bc,
    float* __restrict__ out)                // lp N | ent N | val N | hN B*H | cN B*H
{
    __shared__ float hls[4][128];
    __shared__ float cls[4][128];
    __shared__ float gls[4][512];
    __shared__ float WaS[128*32];
    __shared__ float baS[32];
    __shared__ float WcS[128];
    __shared__ float bcS;

    const int tid = threadIdx.x;
    const int b0 = blockIdx.x * 4;

    // w_hh row tid -> registers
    float wv[128];
    {
        const float4* wr = (const float4*)(w_hh + (size_t)tid * 128);
        #pragma unroll
        for (int q = 0; q < 32; ++q) {
            float4 v = wr[q];
            wv[4*q+0] = v.x; wv[4*q+1] = v.y; wv[4*q+2] = v.z; wv[4*q+3] = v.w;
        }
    }
    for (int i = tid; i < 128*32; i += 512) WaS[i] = Wa[i];
    if (tid < 32)  baS[tid] = ba[tid];
    if (tid < 128) WcS[tid] = Wc[tid];
    if (tid == 0)  bcS = bc[0];

    const int r = tid >> 7;       // 0..3
    const int u = tid & 127;      // 0..127
    hls[r][u] = h0[(size_t)(b0 + r)*128 + u];
    cls[r][u] = c0[(size_t)(b0 + r)*128 + u];

    // t=0 operand preload
    int   dn   = done[b0 + r];
    float xgv0 = __bfloat162float(xg[(size_t)(b0 + 0)*512 + tid]);
    float xgv1 = __bfloat162float(xg[(size_t)(b0 + 1)*512 + tid]);
    float xgv2 = __bfloat162float(xg[(size_t)(b0 + 2)*512 + tid]);
    float xgv3 = __bfloat162float(xg[(size_t)(b0 + 3)*512 + tid]);
    int mcur = 1, acur = 0;
    if (tid < 128) {
        int rr = tid >> 5, j = tid & 31;
        mcur = mask[(size_t)(b0 + rr)*32 + j];
        acur = action[b0 + rr];
    }
    __syncthreads();

    for (int t = 0; t < TT; ++t) {
        const size_t base = (size_t)t * BB + b0;

        // done-based state reset (before gates), done value prefetched
        float keep = dn ? 0.0f : 1.0f;
        hls[r][u] *= keep;
        cls[r][u] *= keep;
        __syncthreads();

        // prefetch t+1 operands (hidden under the FMA loop)
        int   dnn = 0, mn = 1, an = 0;
        float nx0 = 0.f, nx1 = 0.f, nx2 = 0.f, nx3 = 0.f;
        if (t < TT - 1) {
            const size_t basen = base + BB;
            dnn = done[basen + r];
            nx0 = __bfloat162float(xg[(basen + 0)*512 + tid]);
            nx1 = __bfloat162float(xg[(basen + 1)*512 + tid]);
            nx2 = __bfloat162float(xg[(basen + 2)*512 + tid]);
            nx3 = __bfloat162float(xg[(basen + 3)*512 + tid]);
            if (tid < 128) {
                int rr = tid >> 5, j = tid & 31;
                mn = mask[(basen + rr)*32 + j];
                an = action[basen + rr];
            }
        }

        // g[rr][tid] = xg[rr][tid] + sum_k h[rr][k] * w_hh[tid][k]
        float acc0 = xgv0, acc1 = xgv1, acc2 = xgv2, acc3 = xgv3;
        #pragma unroll
        for (int k4 = 0; k4 < 32; ++k4) {
            float4 hv0 = *(const float4*)&hls[0][4*k4];
            float4 hv1 = *(const float4*)&hls[1][4*k4];
            float4 hv2 = *(const float4*)&hls[2][4*k4];
            float4 hv3 = *(const float4*)&hls[3][4*k4];
            acc0 = fmaf(wv[4*k4+0], hv0.x, acc0);
            acc1 = fmaf(wv[4*k4+0], hv1.x, acc1);
            acc2 = fmaf(wv[4*k4+0], hv2.x, acc2);
            acc3 = fmaf(wv[4*k4+0], hv3.x, acc3);
            acc0 = fmaf(wv[4*k4+1], hv0.y, acc0);
            acc1 = fmaf(wv[4*k4+1], hv1.y, acc1);
            acc2 = fmaf(wv[4*k4+1], hv2.y, acc2);
            acc3 = fmaf(wv[4*k4+1], hv3.y, acc3);
            acc0 = fmaf(wv[4*k4+2], hv0.z, acc0);
            acc1 = fmaf(wv[4*k4+2], hv1.z, acc1);
            acc2 = fmaf(wv[4*k4+2], hv2.z, acc2);
            acc3 = fmaf(wv[4*k4+2], hv3.z, acc3);
            acc0 = fmaf(wv[4*k4+3], hv0.w, acc0);
            acc1 = fmaf(wv[4*k4+3], hv1.w, acc1);
            acc2 = fmaf(wv[4*k4+3], hv2.w, acc2);
            acc3 = fmaf(wv[4*k4+3], hv3.w, acc3);
        }
        gls[0][tid] = acc0;
        gls[1][tid] = acc1;
        gls[2][tid] = acc2;
        gls[3][tid] = acc3;
        __syncthreads();

        // gate update (torch order i,f,g,o)
        {
            float gi = gls[r][u];
            float gf = gls[r][128 + u];
            float gg = gls[r][256 + u];
            float go = gls[r][384 + u];
            float cn = sigmoidf_(gf) * cls[r][u] + sigmoidf_(gi) * tanhf_(gg);
            float hn = sigmoidf_(go) * tanhf_(cn);
            cls[r][u] = cn;
            hls[r][u] = hn;
        }
        __syncthreads();

        // heads: threads 0..127 -> (row rr, logit j)
        if (tid < 128) {
            int rr = tid >> 5, j = tid & 31;
            float lg = baS[j];
            #pragma unroll 8
            for (int k = 0; k < 128; ++k)
                lg = fmaf(hls[rr][k], WaS[k*32 + j], lg);
            if (mcur == 0) lg = -1e8f;
            float mx = lg;
            #pragma unroll
            for (int off = 16; off > 0; off >>= 1)
                mx = fmaxf(mx, __shfl_xor(mx, off, 32));
            float e = __expf(lg - mx);
            float s = e;
            #pragma unroll
            for (int off = 16; off > 0; off >>= 1)
                s += __shfl_xor(s, off, 32);
            float lse = __logf(s);
            float logp = lg - mx - lse;
            float p = e / s;
            float entp = -p * logp;
            #pragma unroll
            for (int off = 16; off > 0; off >>= 1)
                entp += __shfl_xor(entp, off, 32);
            if (j == acur) out[base + rr] = logp;                 // lp
            if (j == 0)    out[(size_t)NN + base + rr] = entp;    // entropy
            float vp = 0.0f;
            #pragma unroll
            for (int q = 0; q < 4; ++q)
                vp = fmaf(hls[rr][j*4 + q], WcS[j*4 + q], vp);
            #pragma unroll
            for (int off = 16; off > 0; off >>= 1)
                vp += __shfl_xor(vp, off, 32);
            if (j == 0) out[2*(size_t)NN + base + rr] = vp + bcS;
        }
        __syncthreads();

        // rotate prefetched operands
        xgv0 = nx0; xgv1 = nx1; xgv2 = nx2; xgv3 = nx3;
        dn = dnn;
        if (tid < 128) { mcur = mn; acur = an; }
    }

    // final states hN, cN
    out[3*(size_t)NN + (size_t)(b0 + r)*128 + u] = hls[r][u];
    out[3*(size_t)NN + (size_t)BB*HH + (size_t)(b0 + r)*128 + u] = cls[r][u];
}

extern "C" void kernel_launch(void* const* d_in, const int* in_sizes, int n_in,
                              void* d_out, int out_size, void* d_ws, size_t ws_size,
                              hipStream_t stream) {
    const float* x      = (const float*)d_in[0];
    const int*   done   = (const int*)d_in[1];
    const int*   action = (const int*)d_in[2];
    const int*   mask   = (const int*)d_in[3];
    const float* h0     = (const float*)d_in[4];
    const float* c0     = (const float*)d_in[5];
    const float* W1     = (const float*)d_in[6];
    const float* b1     = (const float*)d_in[7];
    const float* W2     = (const float*)d_in[8];
    const float* b2     = (const float*)d_in[9];
    const float* w_ih   = (const float*)d_in[10];
    const float* w_hh   = (const float*)d_in[11];
    const float* b_ih   = (const float*)d_in[12];
    const float* b_hh   = (const float*)d_in[13];
    const float* Wa     = (const float*)d_in[14];
    const float* ba     = (const float*)d_in[15];
    const float* Wc     = (const float*)d_in[16];
    const float* bc     = (const float*)d_in[17];

    __hip_bfloat16* xg = (__hip_bfloat16*)d_ws;  // [N,512] bf16 = 256 MiB

    trunk_kernel<<<NN/128, 512, 0, stream>>>(x, W1, b1, W2, b2, w_ih, b_ih, b_hh, xg);
    lstm_kernel<<<BB/4, 512, 0, stream>>>(xg, w_hh, done, action, mask, h0, c0,
                                          Wa, ba, Wc, bc, (float*)d_out);
}

// Round 4
// 693.893 us; speedup vs baseline: 4.9423x; 2.1260x over previous
//
#include <hip/hip_runtime.h>
#include <hip/hip_bf16.h>

// Problem constants
#define TT   256
#define BB   1024
#define OBS  64
#define HH   128
#define AA   32
#define NN   (TT*BB)          // 262144

typedef __bf16 bf16x8 __attribute__((ext_vector_type(8)));
typedef float  f32x4  __attribute__((ext_vector_type(4)));

__device__ __forceinline__ float sigmoidf_(float x) {
    return 1.0f / (1.0f + __expf(-x));
}
__device__ __forceinline__ float tanhf_(float x) {
    float ax = fabsf(x);
    float e  = __expf(-2.0f * ax);
    float t  = (1.0f - e) / (1.0f + e);
    return copysignf(t, x);
}
__device__ __forceinline__ __hip_bfloat16 f2b(float v) { return __float2bfloat16(v); }
__device__ __forceinline__ bf16x8 ldb(const __hip_bfloat16* p) {
    return *reinterpret_cast<const bf16x8*>(p);
}
__device__ __forceinline__ f32x4 mm16(bf16x8 a, bf16x8 b, f32x4 c) {
    return __builtin_amdgcn_mfma_f32_16x16x32_bf16(a, b, c, 0, 0, 0);
}

// ---------------------------------------------------------------------------
// Kernel 1 (MFMA bf16, unchanged from round 3, ~85us):
//   hidden = relu(relu(x@W1+b1)@W2+b2); xg = hidden@w_ih.T + (b_ih+b_hh)
// ---------------------------------------------------------------------------
__global__ __launch_bounds__(512) void trunk_kernel(
    const float* __restrict__ x,
    const float* __restrict__ W1, const float* __restrict__ b1,
    const float* __restrict__ W2, const float* __restrict__ b2,
    const float* __restrict__ w_ih,
    const float* __restrict__ b_ih, const float* __restrict__ b_hh,
    __hip_bfloat16* __restrict__ xg)
{
    __shared__ __align__(16) char smem[109568];
    __hip_bfloat16 (*xb)[72]    = (__hip_bfloat16(*)[72])(smem);
    __hip_bfloat16 (*W1T)[72]   = (__hip_bfloat16(*)[72])(smem + 18432);
    __hip_bfloat16 (*W2T)[136]  = (__hip_bfloat16(*)[136])(smem);
    __hip_bfloat16 (*h1b)[136]  = (__hip_bfloat16(*)[136])(smem + 36864);
    __hip_bfloat16 (*h2b)[136]  = (__hip_bfloat16(*)[136])(smem + 71680);
    __hip_bfloat16 (*wihb)[136] = (__hip_bfloat16(*)[136])(smem);
    float* sb1  = (float*)(smem + 106496);
    float* sb2  = sb1 + 128;
    float* sbih = sb2 + 128;

    const int tid  = threadIdx.x;
    const int lane = tid & 63;
    const int w    = tid >> 6;
    const int m0   = w * 16;
    const int lm   = lane & 15;
    const int lk   = (lane >> 4) * 8;
    const size_t r0 = (size_t)blockIdx.x * 128;

    {
        int row = tid >> 2, seg = tid & 3;
        const float4* xs = (const float4*)(x + (r0 + row) * OBS + seg * 16);
        float4 v0 = xs[0], v1 = xs[1], v2 = xs[2], v3 = xs[3];
        union { bf16x8 v[2]; __hip_bfloat16 h[16]; } u;
        u.h[0]=f2b(v0.x); u.h[1]=f2b(v0.y); u.h[2]=f2b(v0.z); u.h[3]=f2b(v0.w);
        u.h[4]=f2b(v1.x); u.h[5]=f2b(v1.y); u.h[6]=f2b(v1.z); u.h[7]=f2b(v1.w);
        u.h[8]=f2b(v2.x); u.h[9]=f2b(v2.y); u.h[10]=f2b(v2.z); u.h[11]=f2b(v2.w);
        u.h[12]=f2b(v3.x); u.h[13]=f2b(v3.y); u.h[14]=f2b(v3.z); u.h[15]=f2b(v3.w);
        *(bf16x8*)&xb[row][seg*16]     = u.v[0];
        *(bf16x8*)&xb[row][seg*16 + 8] = u.v[1];
    }
    #pragma unroll
    for (int kk = 0; kk < 4; ++kk) {
        int k = (tid >> 5) + kk * 16;
        int n0 = (tid & 31) * 4;
        float4 wv4 = *(const float4*)(W1 + k * HH + n0);
        W1T[n0+0][k] = f2b(wv4.x); W1T[n0+1][k] = f2b(wv4.y);
        W1T[n0+2][k] = f2b(wv4.z); W1T[n0+3][k] = f2b(wv4.w);
    }
    if (tid < 128) { sb1[tid] = b1[tid]; sb2[tid] = b2[tid]; }
    sbih[tid] = b_ih[tid] + b_hh[tid];
    __syncthreads();

    {
        bf16x8 a0 = ldb(&xb[m0 + lm][lk]);
        bf16x8 a1 = ldb(&xb[m0 + lm][32 + lk]);
        #pragma unroll
        for (int ct = 0; ct < 8; ++ct) {
            bf16x8 bv0 = ldb(&W1T[ct*16 + lm][lk]);
            bf16x8 bv1 = ldb(&W1T[ct*16 + lm][32 + lk]);
            f32x4 acc = {0.f, 0.f, 0.f, 0.f};
            acc = mm16(a0, bv0, acc);
            acc = mm16(a1, bv1, acc);
            float bias = sb1[ct*16 + lm];
            int rb = m0 + (lane >> 4) * 4;
            #pragma unroll
            for (int rr = 0; rr < 4; ++rr)
                h1b[rb + rr][ct*16 + lm] = f2b(fmaxf(acc[rr] + bias, 0.f));
        }
    }
    __syncthreads();

    #pragma unroll
    for (int kk = 0; kk < 8; ++kk) {
        int k = (tid >> 5) + kk * 16;
        int n0 = (tid & 31) * 4;
        float4 wv4 = *(const float4*)(W2 + k * HH + n0);
        W2T[n0+0][k] = f2b(wv4.x); W2T[n0+1][k] = f2b(wv4.y);
        W2T[n0+2][k] = f2b(wv4.z); W2T[n0+3][k] = f2b(wv4.w);
    }
    __syncthreads();

    {
        bf16x8 a[4];
        #pragma unroll
        for (int kt = 0; kt < 4; ++kt) a[kt] = ldb(&h1b[m0 + lm][kt*32 + lk]);
        #pragma unroll
        for (int ct = 0; ct < 8; ++ct) {
            f32x4 acc = {0.f, 0.f, 0.f, 0.f};
            #pragma unroll
            for (int kt = 0; kt < 4; ++kt)
                acc = mm16(a[kt], ldb(&W2T[ct*16 + lm][kt*32 + lk]), acc);
            float bias = sb2[ct*16 + lm];
            int rb = m0 + (lane >> 4) * 4;
            #pragma unroll
            for (int rr = 0; rr < 4; ++rr)
                h2b[rb + rr][ct*16 + lm] = f2b(fmaxf(acc[rr] + bias, 0.f));
        }
    }
    __syncthreads();

    bf16x8 a3[4];
    #pragma unroll
    for (int kt = 0; kt < 4; ++kt) a3[kt] = ldb(&h2b[m0 + lm][kt*32 + lk]);

    for (int jc = 0; jc < 2; ++jc) {
        #pragma unroll
        for (int jj = 0; jj < 4; ++jj) {
            int jrow = jj * 64 + (tid >> 3);
            int seg = tid & 7;
            const float4* ws = (const float4*)(w_ih + (size_t)(jc*256 + jrow) * HH + seg * 16);
            float4 v0 = ws[0], v1 = ws[1], v2 = ws[2], v3 = ws[3];
            union { bf16x8 v[2]; __hip_bfloat16 h[16]; } u;
            u.h[0]=f2b(v0.x); u.h[1]=f2b(v0.y); u.h[2]=f2b(v0.z); u.h[3]=f2b(v0.w);
            u.h[4]=f2b(v1.x); u.h[5]=f2b(v1.y); u.h[6]=f2b(v1.z); u.h[7]=f2b(v1.w);
            u.h[8]=f2b(v2.x); u.h[9]=f2b(v2.y); u.h[10]=f2b(v2.z); u.h[11]=f2b(v2.w);
            u.h[12]=f2b(v3.x); u.h[13]=f2b(v3.y); u.h[14]=f2b(v3.z); u.h[15]=f2b(v3.w);
            *(bf16x8*)&wihb[jrow][seg*16]     = u.v[0];
            *(bf16x8*)&wihb[jrow][seg*16 + 8] = u.v[1];
        }
        __syncthreads();

        #pragma unroll
        for (int ct = 0; ct < 16; ++ct) {
            f32x4 acc = {0.f, 0.f, 0.f, 0.f};
            #pragma unroll
            for (int kt = 0; kt < 4; ++kt)
                acc = mm16(a3[kt], ldb(&wihb[ct*16 + lm][kt*32 + lk]), acc);
            int jcol = jc*256 + ct*16 + lm;
            float bias = sbih[jcol];
            size_t rb = r0 + m0 + (lane >> 4) * 4;
            #pragma unroll
            for (int rr = 0; rr < 4; ++rr)
                xg[(rb + rr) * 512 + jcol] = f2b(acc[rr] + bias);
        }
        __syncthreads();
    }
}

// ---------------------------------------------------------------------------
// Kernel 2: MFMA LSTM scan + pipelined MFMA heads.
// 256 blocks x 512 threads (8 waves); block owns 4 batch rows (padded to 16
// in the MFMA tiles). Per step:
//   phase A: G[512x16] = w_hh(bf16, VGPR A-frags) x h-tile(bf16 LDS B-frags,
//            done-masked in-register); heads for step t-1 off the raw h-tile.
//   phase B: gate update (c in VGPRs, g from LDS + prefetched xg);
//            softmax/entropy/value for step t-1 on threads 0..127.
// w_hh A-frag: gate row = lane&15, k=(lane>>4)*8+i. h B-frag: batch col =
// lane&15. D: col=lane&15 (batch), row=(lane>>4)*4+reg (gate) [m89-verified].
// ---------------------------------------------------------------------------
__global__ __launch_bounds__(512, 1) void lstm_kernel(
    const __hip_bfloat16* __restrict__ xg,  // [N,512] bf16 (bias included)
    const float* __restrict__ w_hh,         // [512,128]
    const int* __restrict__ done,           // [N]
    const int* __restrict__ action,         // [N]
    const int* __restrict__ mask,           // [N,32] bool as int32
    const float* __restrict__ h0,
    const float* __restrict__ c0,
    const float* __restrict__ Wa,           // [128,32]
    const float* __restrict__ ba,
    const float* __restrict__ Wc,           // [128]
    const float* __restrict__ bc,
    float* __restrict__ out)                // lp N | ent N | val N | hN B*H | cN B*H
{
    __shared__ __align__(16) __hip_bfloat16 htile[16][136]; // raw h_t (bf16)
    __shared__ __align__(16) float gls[16][548];            // gates [batch][512]
    __shared__ __align__(16) float lls[16][52];             // heads [batch][33+pad]

    const int tid  = threadIdx.x;
    const int lane = tid & 63;
    const int w    = tid >> 6;       // wave 0..7
    const int lm   = lane & 15;      // batch col (0..3 valid) / A row
    const int lko  = lane >> 4;      // k-octet 0..3
    const int b0   = blockIdx.x * 4;
    const int r    = tid >> 7;       // 0..3 batch row (gate update)
    const int u    = tid & 127;      // hidden unit
    const int rr   = tid >> 5;       // softmax: batch row (tid<128)
    const int j    = tid & 31;       // softmax: logit idx

    // ---- static A-fragments: w_hh rows [w*64, w*64+64) -> 64 VGPR ----
    bf16x8 wf[4][4];
    #pragma unroll
    for (int gt = 0; gt < 4; ++gt) {
        #pragma unroll
        for (int kt = 0; kt < 4; ++kt) {
            const float* p = w_hh + (size_t)(w*64 + gt*16 + lm)*HH + kt*32 + lko*8;
            float4 a = *(const float4*)p;
            float4 b = *(const float4*)(p + 4);
            union { bf16x8 v; __hip_bfloat16 h[8]; } uu;
            uu.h[0]=f2b(a.x); uu.h[1]=f2b(a.y); uu.h[2]=f2b(a.z); uu.h[3]=f2b(a.w);
            uu.h[4]=f2b(b.x); uu.h[5]=f2b(b.y); uu.h[6]=f2b(b.z); uu.h[7]=f2b(b.w);
            wf[gt][kt] = uu.v;
        }
    }
    // ---- head A-fragments (waves 0,1: Wa cols; wave 2: Wc in row 0) ----
    bf16x8 hf[4];
    if (w < 2) {
        #pragma unroll
        for (int kt = 0; kt < 4; ++kt) {
            union { bf16x8 v; __hip_bfloat16 h[8]; } uu;
            #pragma unroll
            for (int i = 0; i < 8; ++i)
                uu.h[i] = f2b(Wa[(size_t)(kt*32 + lko*8 + i)*AA + w*16 + lm]);
            hf[kt] = uu.v;
        }
    } else if (w == 2) {
        #pragma unroll
        for (int kt = 0; kt < 4; ++kt) {
            union { bf16x8 v; __hip_bfloat16 h[8]; } uu;
            #pragma unroll
            for (int i = 0; i < 8; ++i)
                uu.h[i] = (lm == 0) ? f2b(Wc[kt*32 + lko*8 + i]) : f2b(0.0f);
            hf[kt] = uu.v;
        }
    }

    float baR = 0.f, bcR = 0.f;
    if (tid < 128) { baR = ba[j]; bcR = bc[0]; }

    // ---- init h-tile (raw h0, rows 4..15 zero), c/h regs ----
    htile[r][u] = f2b(h0[(size_t)(b0 + r)*HH + u]);
    for (int idx = tid; idx < 12*136; idx += 512)
        (&htile[4][0])[idx] = f2b(0.0f);
    float c_reg = c0[(size_t)(b0 + r)*HH + u];
    float h_reg = h0[(size_t)(b0 + r)*HH + u];

    // ---- prefetch for iter 0 ----
    int dnv_c = done[b0 + (lm < 4 ? lm : 3)];   // per-lane batch done (gate mask)
    int dnr_c = done[b0 + r];                   // per-thread row done (c reset)
    float xgc[4];
    #pragma unroll
    for (int q = 0; q < 4; ++q)
        xgc[q] = __bfloat162float(xg[(size_t)(b0 + r)*512 + q*128 + u]);
    int msk_c = 1, act_c = 0;

    __syncthreads();

    for (int it = 0; it <= TT; ++it) {
        const size_t base = (size_t)it * BB + b0;

        // prefetch next-iter operands (hidden under MFMA)
        int dnv_n = 0, dnr_n = 0, msk_n = 1, act_n = 0;
        float xgn[4] = {0.f, 0.f, 0.f, 0.f};
        if (it < TT - 1) {
            dnv_n = done[base + BB + (lm < 4 ? lm : 3)];
            dnr_n = done[base + BB + r];
            #pragma unroll
            for (int q = 0; q < 4; ++q)
                xgn[q] = __bfloat162float(xg[(base + BB + r)*512 + q*128 + u]);
        }
        if (it < TT && tid < 128) {          // for softmax of step `it` (next iter)
            msk_n = mask[(base + rr)*32 + j];
            act_n = action[base + rr];
        }

        // ---- phase A: MFMA ----
        bf16x8 hb[4];
        #pragma unroll
        for (int kt = 0; kt < 4; ++kt)
            hb[kt] = ldb(&htile[lm][kt*32 + lko*8]);

        if (it < TT) {
            // done-reset folded into B-frags (keep in {0,1} -> word select)
            bf16x8 hm[4];
            #pragma unroll
            for (int kt = 0; kt < 4; ++kt) {
                union { bf16x8 v; int w4[4]; } um;
                um.v = hb[kt];
                #pragma unroll
                for (int q = 0; q < 4; ++q)
                    um.w4[q] = dnv_c ? 0 : um.w4[q];
                hm[kt] = um.v;
            }
            f32x4 acc[4];
            #pragma unroll
            for (int gt = 0; gt < 4; ++gt) acc[gt] = (f32x4){0.f, 0.f, 0.f, 0.f};
            #pragma unroll
            for (int kt = 0; kt < 4; ++kt)
                #pragma unroll
                for (int gt = 0; gt < 4; ++gt)
                    acc[gt] = mm16(wf[gt][kt], hm[kt], acc[gt]);
            #pragma unroll
            for (int gt = 0; gt < 4; ++gt)
                *(f32x4*)&gls[lm][(w*4 + gt)*16 + lko*4] = acc[gt];
        }
        if (it >= 1 && w < 3) {              // heads for step it-1 (raw h)
            f32x4 hacc = {0.f, 0.f, 0.f, 0.f};
            #pragma unroll
            for (int kt = 0; kt < 4; ++kt)
                hacc = mm16(hf[kt], hb[kt], hacc);
            *(f32x4*)&lls[lm][w*16 + lko*4] = hacc;
        }
        __syncthreads();

        // ---- phase B ----
        if (it < TT) {
            float keep = dnr_c ? 0.0f : 1.0f;
            float gi = gls[r][u]       + xgc[0];
            float gf = gls[r][128 + u] + xgc[1];
            float gg = gls[r][256 + u] + xgc[2];
            float go = gls[r][384 + u] + xgc[3];
            float cp = c_reg * keep;
            float cn = sigmoidf_(gf) * cp + sigmoidf_(gi) * tanhf_(gg);
            float hn = sigmoidf_(go) * tanhf_(cn);
            c_reg = cn; h_reg = hn;
            htile[r][u] = f2b(hn);
        }
        if (it >= 1 && tid < 128) {          // softmax/outputs for step it-1
            const size_t bs = base - BB;
            float lg = lls[rr][j] + baR;
            if (msk_c == 0) lg = -1e8f;
            float mx = lg;
            #pragma unroll
            for (int off = 16; off > 0; off >>= 1)
                mx = fmaxf(mx, __shfl_xor(mx, off, 32));
            float e = __expf(lg - mx);
            float s = e;
            #pragma unroll
            for (int off = 16; off > 0; off >>= 1)
                s += __shfl_xor(s, off, 32);
            float lse = __logf(s);
            float logp = lg - mx - lse;
            float p = e / s;
            float entp = -p * logp;
            #pragma unroll
            for (int off = 16; off > 0; off >>= 1)
                entp += __shfl_xor(entp, off, 32);
            if (j == act_c) out[bs + rr] = logp;
            if (j == 0) {
                out[(size_t)NN + bs + rr] = entp;
                out[2*(size_t)NN + bs + rr] = lls[rr][32] + bcR;
            }
        }
        __syncthreads();

        dnv_c = dnv_n; dnr_c = dnr_n;
        xgc[0] = xgn[0]; xgc[1] = xgn[1]; xgc[2] = xgn[2]; xgc[3] = xgn[3];
        msk_c = msk_n; act_c = act_n;
    }

    // final states
    out[3*(size_t)NN + (size_t)(b0 + r)*HH + u] = h_reg;
    out[3*(size_t)NN + (size_t)BB*HH + (size_t)(b0 + r)*HH + u] = c_reg;
}

extern "C" void kernel_launch(void* const* d_in, const int* in_sizes, int n_in,
                              void* d_out, int out_size, void* d_ws, size_t ws_size,
                              hipStream_t stream) {
    const float* x      = (const float*)d_in[0];
    const int*   done   = (const int*)d_in[1];
    const int*   action = (const int*)d_in[2];
    const int*   mask   = (const int*)d_in[3];
    const float* h0     = (const float*)d_in[4];
    const float* c0     = (const float*)d_in[5];
    const float* W1     = (const float*)d_in[6];
    const float* b1     = (const float*)d_in[7];
    const float* W2     = (const float*)d_in[8];
    const float* b2     = (const float*)d_in[9];
    const float* w_ih   = (const float*)d_in[10];
    const float* w_hh   = (const float*)d_in[11];
    const float* b_ih   = (const float*)d_in[12];
    const float* b_hh   = (const float*)d_in[13];
    const float* Wa     = (const float*)d_in[14];
    const float* ba     = (const float*)d_in[15];
    const float* Wc     = (const float*)d_in[16];
    const float* bc     = (const float*)d_in[17];

    __hip_bfloat16* xg = (__hip_bfloat16*)d_ws;  // [N,512] bf16 = 256 MiB

    trunk_kernel<<<NN/128, 512, 0, stream>>>(x, W1, b1, W2, b2, w_ih, b_ih, b_hh, xg);
    lstm_kernel<<<BB/4, 512, 0, stream>>>(xg, w_hh, done, action, mask, h0, c0,
                                          Wa, ba, Wc, bc, (float*)d_out);
}